// Round 1
// baseline (1502.969 us; speedup 1.0000x reference)
//
#include <hip/hip_runtime.h>
#include <cstdint>
#include <cstddef>

// W8A8LinearStatic: out[m][n] = (sum_k round(x[m][k]/s_act) * W[n][k]) * out_scales[n]
// M=8192 (B*S), N=11008, K=4096.
// Strategy: q_x fits fp16 exactly (|q|<2048 integer), W fits fp16 exactly (|w|<=127)
// -> single f16 MFMA GEMM, fp32 accumulate == exact vs reference.
// Path A (ws_size >= 157MB): convert x->fp16, W->fp16 in d_ws, then
//   m97-style 128x128 tile GEMM with global_load_lds(16B) staging.
// Path B (fallback): same GEMM with register staging + inline conversion.

#define M_DIM 8192
#define N_DIM 11008
#define K_DIM 4096

typedef _Float16 half8 __attribute__((ext_vector_type(8)));
typedef float    f32x4 __attribute__((ext_vector_type(4)));

#define GLOBAL_AS(p) ((const __attribute__((address_space(1))) void*)(p))
#define LDS_AS(p)    ((__attribute__((address_space(3))) void*)(p))

// ---------------- quantize activations: q = rint(x * (1/s)), store fp16 ----------------
__global__ __launch_bounds__(256) void quant_x_kernel(
    const float* __restrict__ x, const float* __restrict__ act_s,
    _Float16* __restrict__ qx)
{
    const float inv = 1.0f / act_s[0];
    size_t idx = ((size_t)blockIdx.x * 256u + threadIdx.x) * 8u;
    const float4* p = (const float4*)(x + idx);
    float4 v0 = p[0];
    float4 v1 = p[1];
    half8 h;
    h[0] = (_Float16)rintf(v0.x * inv);
    h[1] = (_Float16)rintf(v0.y * inv);
    h[2] = (_Float16)rintf(v0.z * inv);
    h[3] = (_Float16)rintf(v0.w * inv);
    h[4] = (_Float16)rintf(v1.x * inv);
    h[5] = (_Float16)rintf(v1.y * inv);
    h[6] = (_Float16)rintf(v1.z * inv);
    h[7] = (_Float16)rintf(v1.w * inv);
    *(half8*)(qx + idx) = h;
}

// ---------------- convert weights: int32 (int8-valued) -> fp16 ----------------
__global__ __launch_bounds__(256) void quant_w_kernel(
    const int* __restrict__ w, _Float16* __restrict__ qw)
{
    size_t idx = ((size_t)blockIdx.x * 256u + threadIdx.x) * 8u;
    const int4* p = (const int4*)(w + idx);
    int4 v0 = p[0];
    int4 v1 = p[1];
    half8 h;
    h[0] = (_Float16)v0.x;
    h[1] = (_Float16)v0.y;
    h[2] = (_Float16)v0.z;
    h[3] = (_Float16)v0.w;
    h[4] = (_Float16)v1.x;
    h[5] = (_Float16)v1.y;
    h[6] = (_Float16)v1.z;
    h[7] = (_Float16)v1.w;
    *(half8*)(qw + idx) = h;
}

// ---------------- main GEMM ----------------
// Tile: BM=BN=128, BK=64. Block = 256 threads = 4 waves (2x2), each wave 64x64
// = 4x4 frags of 16x16, mfma_f32_16x16x32_f16.
// LDS layout (per operand): 128 rows x 8 kchunks of 8 halves (16B).
//   slot(row, kchunk) = row*8 + (kchunk ^ (row & 7))   <- XOR swizzle:
//   - staging writes land at wave-uniform base + lane*16 (global_load_lds OK)
//   - frag ds_read_b128: 8 lanes per 4-bank group (balanced, conflict-free)
template<bool FROMWS>
__global__ __launch_bounds__(256, 2) void w8a8_gemm(
    const _Float16* __restrict__ Aq, const _Float16* __restrict__ Bq,
    const float* __restrict__ X, const int* __restrict__ Wt,
    const float* __restrict__ act_s, const float* __restrict__ out_s,
    float* __restrict__ out)
{
    __shared__ _Float16 As[128 * 64];
    __shared__ _Float16 Bs[128 * 64];

    const int tid  = threadIdx.x;
    const int lane = tid & 63;
    const int wv   = tid >> 6;          // 0..3
    const int wrow = (wv >> 1) * 64;
    const int wcol = (wv & 1) * 64;
    const int m16  = lane & 15;
    const int q4   = lane >> 4;         // 0..3
    const int xm   = m16 & 7;

    const int row0 = blockIdx.y * 128;
    const int col0 = blockIdx.x * 128;

    // staging mapping: slot sidx = tid + i*256 covers (row = sidx>>3, jx = sidx&7),
    // kchunk j = jx ^ (row&7). (tid>>3)&7 is invariant across issues i.
    const int srow = tid >> 3;                 // 0..31, +32 per issue
    const int sj   = (tid & 7) ^ (srow & 7);   // swizzled k-chunk for this thread

    f32x4 acc[4][4];
#pragma unroll
    for (int i = 0; i < 4; ++i)
#pragma unroll
        for (int j = 0; j < 4; ++j)
            acc[i][j] = (f32x4)0.0f;

    float inv = 0.0f;
    if (!FROMWS) inv = 1.0f / act_s[0];

    const _Float16* aSrc = nullptr;
    const _Float16* bSrc = nullptr;
    const float*    xSrc = nullptr;
    const int*      wSrc = nullptr;
    if (FROMWS) {
        aSrc = Aq + (size_t)(row0 + srow) * K_DIM + sj * 8;
        bSrc = Bq + (size_t)(col0 + srow) * K_DIM + sj * 8;
    } else {
        xSrc = X  + (size_t)(row0 + srow) * K_DIM + sj * 8;
        wSrc = Wt + (size_t)(col0 + srow) * K_DIM + sj * 8;
    }

    _Float16* aDst = As + tid * 8;
    _Float16* bDst = Bs + tid * 8;

    for (int kk = 0; kk < K_DIM / 64; ++kk) {
        if (FROMWS) {
#pragma unroll
            for (int i = 0; i < 4; ++i) {
                __builtin_amdgcn_global_load_lds(
                    GLOBAL_AS(aSrc + (size_t)i * 32 * K_DIM),
                    LDS_AS(aDst + i * 256 * 8), 16, 0, 0);
            }
#pragma unroll
            for (int i = 0; i < 4; ++i) {
                __builtin_amdgcn_global_load_lds(
                    GLOBAL_AS(bSrc + (size_t)i * 32 * K_DIM),
                    LDS_AS(bDst + i * 256 * 8), 16, 0, 0);
            }
            aSrc += 64;
            bSrc += 64;
        } else {
#pragma unroll
            for (int i = 0; i < 4; ++i) {
                const float4* p = (const float4*)(xSrc + (size_t)i * 32 * K_DIM);
                float4 v0 = p[0];
                float4 v1 = p[1];
                half8 h;
                h[0] = (_Float16)rintf(v0.x * inv);
                h[1] = (_Float16)rintf(v0.y * inv);
                h[2] = (_Float16)rintf(v0.z * inv);
                h[3] = (_Float16)rintf(v0.w * inv);
                h[4] = (_Float16)rintf(v1.x * inv);
                h[5] = (_Float16)rintf(v1.y * inv);
                h[6] = (_Float16)rintf(v1.z * inv);
                h[7] = (_Float16)rintf(v1.w * inv);
                *(half8*)(aDst + i * 256 * 8) = h;
            }
#pragma unroll
            for (int i = 0; i < 4; ++i) {
                const int4* p = (const int4*)(wSrc + (size_t)i * 32 * K_DIM);
                int4 v0 = p[0];
                int4 v1 = p[1];
                half8 h;
                h[0] = (_Float16)v0.x;
                h[1] = (_Float16)v0.y;
                h[2] = (_Float16)v0.z;
                h[3] = (_Float16)v0.w;
                h[4] = (_Float16)v1.x;
                h[5] = (_Float16)v1.y;
                h[6] = (_Float16)v1.z;
                h[7] = (_Float16)v1.w;
                *(half8*)(bDst + i * 256 * 8) = h;
            }
            xSrc += 64;
            wSrc += 64;
        }
        __syncthreads();   // drains vmcnt(0)+lgkmcnt(0) then barrier

#pragma unroll
        for (int s = 0; s < 2; ++s) {
            half8 af[4], bf[4];
            const int chunk = (s * 4 + q4) ^ xm;   // swizzled kchunk for this lane
#pragma unroll
            for (int t = 0; t < 4; ++t) {
                af[t] = *(const half8*)(As + (wrow + t * 16 + m16) * 64 + chunk * 8);
                bf[t] = *(const half8*)(Bs + (wcol + t * 16 + m16) * 64 + chunk * 8);
            }
#pragma unroll
            for (int ti = 0; ti < 4; ++ti)
#pragma unroll
                for (int tj = 0; tj < 4; ++tj)
                    acc[ti][tj] = __builtin_amdgcn_mfma_f32_16x16x32_f16(
                        af[ti], bf[tj], acc[ti][tj], 0, 0, 0);
        }
        __syncthreads();
    }

    // epilogue: D mapping (m89-verified): col(n) = lane&15, row(m) = (lane>>4)*4 + reg
#pragma unroll
    for (int tj = 0; tj < 4; ++tj) {
        const int n = col0 + wcol + tj * 16 + m16;
        const float sc = out_s[n];
#pragma unroll
        for (int ti = 0; ti < 4; ++ti) {
            const int rbase = row0 + wrow + ti * 16 + q4 * 4;
#pragma unroll
            for (int r = 0; r < 4; ++r) {
                out[(size_t)(rbase + r) * N_DIM + n] = acc[ti][tj][r] * sc;
            }
        }
    }
}

extern "C" void kernel_launch(void* const* d_in, const int* in_sizes, int n_in,
                              void* d_out, int out_size, void* d_ws, size_t ws_size,
                              hipStream_t stream) {
    const float* x     = (const float*)d_in[0];
    const int*   w     = (const int*)d_in[1];
    const float* act_s = (const float*)d_in[2];
    const float* out_s = (const float*)d_in[3];
    float* out = (float*)d_out;

    const size_t bytesA = (size_t)M_DIM * K_DIM * sizeof(_Float16);   // 64 MiB
    const size_t bytesB = (size_t)N_DIM * K_DIM * sizeof(_Float16);   // 86 MiB

    dim3 grid(N_DIM / 128, M_DIM / 128);   // (86, 64)

    if (ws_size >= bytesA + bytesB) {
        _Float16* Aq = (_Float16*)d_ws;
        _Float16* Bq = (_Float16*)((char*)d_ws + bytesA);
        quant_x_kernel<<<(int)(((size_t)M_DIM * K_DIM) / 2048), 256, 0, stream>>>(x, act_s, Aq);
        quant_w_kernel<<<(int)(((size_t)N_DIM * K_DIM) / 2048), 256, 0, stream>>>(w, Bq);
        w8a8_gemm<true><<<grid, 256, 0, stream>>>(Aq, Bq, nullptr, nullptr, act_s, out_s, out);
    } else {
        w8a8_gemm<false><<<grid, 256, 0, stream>>>(nullptr, nullptr, x, w, act_s, out_s, out);
    }
}

// Round 2
// 1378.729 us; speedup vs baseline: 1.0901x; 1.0901x over previous
//
#include <hip/hip_runtime.h>
#include <cstdint>
#include <cstddef>

// W8A8LinearStatic: out[m][n] = (sum_k round(x[m][k]/s_act) * W[n][k]) * out_scales[n]
// M=8192 (B*S), N=11008, K=4096.
// fp16 GEMM (exact: |q_x|<2048 integer, |W|<=127), m97-style 128x128x64 tiles,
// global_load_lds(16B) staging, XOR-swizzled LDS.
// R2: grouped+XCD-chunked tile order (L2/L3 residency), launch_bounds(256,4)
//     (4 blocks/CU), nontemporal epilogue stores (don't evict A/B panels).

#define M_DIM 8192
#define N_DIM 11008
#define K_DIM 4096

#define TM_TILES 64            // M/128
#define TN_TILES 86            // N/128
#define N_BLOCKS (TM_TILES * TN_TILES)   // 5504
#define GROUP_M 16             // tile-rows per group (column-major inside group)

typedef _Float16 half8 __attribute__((ext_vector_type(8)));
typedef float    f32x4 __attribute__((ext_vector_type(4)));

#define GLOBAL_AS(p) ((const __attribute__((address_space(1))) void*)(p))
#define LDS_AS(p)    ((__attribute__((address_space(3))) void*)(p))

// ---------------- quantize activations: q = rint(x * (1/s)), store fp16 ----------------
__global__ __launch_bounds__(256) void quant_x_kernel(
    const float* __restrict__ x, const float* __restrict__ act_s,
    _Float16* __restrict__ qx)
{
    const float inv = 1.0f / act_s[0];
    size_t idx = ((size_t)blockIdx.x * 256u + threadIdx.x) * 8u;
    const float4* p = (const float4*)(x + idx);
    float4 v0 = p[0];
    float4 v1 = p[1];
    half8 h;
    h[0] = (_Float16)rintf(v0.x * inv);
    h[1] = (_Float16)rintf(v0.y * inv);
    h[2] = (_Float16)rintf(v0.z * inv);
    h[3] = (_Float16)rintf(v0.w * inv);
    h[4] = (_Float16)rintf(v1.x * inv);
    h[5] = (_Float16)rintf(v1.y * inv);
    h[6] = (_Float16)rintf(v1.z * inv);
    h[7] = (_Float16)rintf(v1.w * inv);
    *(half8*)(qx + idx) = h;
}

// ---------------- convert weights: int32 (int8-valued) -> fp16 ----------------
__global__ __launch_bounds__(256) void quant_w_kernel(
    const int* __restrict__ w, _Float16* __restrict__ qw)
{
    size_t idx = ((size_t)blockIdx.x * 256u + threadIdx.x) * 8u;
    const int4* p = (const int4*)(w + idx);
    int4 v0 = p[0];
    int4 v1 = p[1];
    half8 h;
    h[0] = (_Float16)v0.x;
    h[1] = (_Float16)v0.y;
    h[2] = (_Float16)v0.z;
    h[3] = (_Float16)v0.w;
    h[4] = (_Float16)v1.x;
    h[5] = (_Float16)v1.y;
    h[6] = (_Float16)v1.z;
    h[7] = (_Float16)v1.w;
    *(half8*)(qw + idx) = h;
}

// ---------------- main GEMM ----------------
// Block = 256 threads = 4 waves (2x2), each wave 64x64 = 4x4 frags of
// 16x16x32_f16. LDS per operand: 128 rows x 8 kchunks of 16B,
// slot(row,kc) = row*8 + (kc ^ (row&7))  (XOR swizzle: staging writes stay
// wave-uniform-base+lane*16; ds_read_b128 spreads over all bank groups).
__global__ __launch_bounds__(256, 4) void w8a8_gemm(
    const _Float16* __restrict__ Aq, const _Float16* __restrict__ Bq,
    const float* __restrict__ out_s, float* __restrict__ out)
{
    __shared__ _Float16 As[128 * 64];
    __shared__ _Float16 Bs[128 * 64];

    const int tid  = threadIdx.x;
    const int lane = tid & 63;
    const int wv   = tid >> 6;          // 0..3
    const int wrow = (wv >> 1) * 64;
    const int wcol = (wv & 1) * 64;
    const int m16  = lane & 15;
    const int q4   = lane >> 4;         // 0..3
    const int xm   = m16 & 7;

    // ---- tile mapping: XCD-chunked grouped order ----
    // id%8 ~ XCD (round-robin dispatch heuristic); each XCD owns a contiguous
    // span of the grouped sequence. Grouped order: GROUP_M tile-rows per group,
    // column-major inside the group -> GROUP_M consecutive tiles share a B
    // panel (stays in that XCD's 4MiB L2); concurrent working set across the
    // chip ~ 16 A-panels + ~32 B-panels = ~48 MiB, resident in L3.
    {
    }
    const int id   = blockIdx.x;
    const int gid  = (id & 7) * (N_BLOCKS / 8) + (id >> 3);
    const int gsz  = GROUP_M * TN_TILES;            // 1376
    const int grp  = gid / gsz;
    const int rem  = gid - grp * gsz;
    const int tn   = rem / GROUP_M;
    const int tm   = grp * GROUP_M + (rem - tn * GROUP_M);

    const int row0 = tm * 128;
    const int col0 = tn * 128;

    // staging: slot sidx = tid + i*256 -> (row = sidx>>3, kc = (sidx&7) ^ (row&7))
    const int srow = tid >> 3;                 // 0..31, +32 per issue
    const int sj   = (tid & 7) ^ (srow & 7);   // swizzled k-chunk for this thread

    f32x4 acc[4][4];
#pragma unroll
    for (int i = 0; i < 4; ++i)
#pragma unroll
        for (int j = 0; j < 4; ++j)
            acc[i][j] = (f32x4)0.0f;

    const _Float16* aSrc = Aq + (size_t)(row0 + srow) * K_DIM + sj * 8;
    const _Float16* bSrc = Bq + (size_t)(col0 + srow) * K_DIM + sj * 8;

    _Float16* aDst = As + tid * 8;
    _Float16* bDst = Bs + tid * 8;

    for (int kk = 0; kk < K_DIM / 64; ++kk) {
#pragma unroll
        for (int i = 0; i < 4; ++i) {
            __builtin_amdgcn_global_load_lds(
                GLOBAL_AS(aSrc + (size_t)i * 32 * K_DIM),
                LDS_AS(aDst + i * 256 * 8), 16, 0, 0);
        }
#pragma unroll
        for (int i = 0; i < 4; ++i) {
            __builtin_amdgcn_global_load_lds(
                GLOBAL_AS(bSrc + (size_t)i * 32 * K_DIM),
                LDS_AS(bDst + i * 256 * 8), 16, 0, 0);
        }
        aSrc += 64;
        bSrc += 64;

        __syncthreads();   // drains vmcnt(0)+lgkmcnt(0) then barrier

#pragma unroll
        for (int s = 0; s < 2; ++s) {
            half8 af[4], bf[4];
            const int chunk = (s * 4 + q4) ^ xm;   // swizzled kchunk for this lane
#pragma unroll
            for (int t = 0; t < 4; ++t) {
                af[t] = *(const half8*)(As + (wrow + t * 16 + m16) * 64 + chunk * 8);
                bf[t] = *(const half8*)(Bs + (wcol + t * 16 + m16) * 64 + chunk * 8);
            }
#pragma unroll
            for (int ti = 0; ti < 4; ++ti)
#pragma unroll
                for (int tj = 0; tj < 4; ++tj)
                    acc[ti][tj] = __builtin_amdgcn_mfma_f32_16x16x32_f16(
                        af[ti], bf[tj], acc[ti][tj], 0, 0, 0);
        }
        __syncthreads();
    }

    // epilogue: D mapping: col(n) = lane&15, row(m) = (lane>>4)*4 + reg.
    // Nontemporal stores: the 360MB output stream must not evict A/B panels.
#pragma unroll
    for (int tj = 0; tj < 4; ++tj) {
        const int n = col0 + wcol + tj * 16 + m16;
        const float sc = out_s[n];
#pragma unroll
        for (int ti = 0; ti < 4; ++ti) {
            const int rbase = row0 + wrow + ti * 16 + q4 * 4;
#pragma unroll
            for (int r = 0; r < 4; ++r) {
                __builtin_nontemporal_store(acc[ti][tj][r] * sc,
                    out + (size_t)(rbase + r) * N_DIM + n);
            }
        }
    }
}

// fallback (ws too small): inline-converting GEMM, register staging
__global__ __launch_bounds__(256, 2) void w8a8_gemm_fb(
    const float* __restrict__ X, const int* __restrict__ Wt,
    const float* __restrict__ act_s, const float* __restrict__ out_s,
    float* __restrict__ out)
{
    __shared__ _Float16 As[128 * 64];
    __shared__ _Float16 Bs[128 * 64];

    const int tid  = threadIdx.x;
    const int lane = tid & 63;
    const int wv   = tid >> 6;
    const int wrow = (wv >> 1) * 64;
    const int wcol = (wv & 1) * 64;
    const int m16  = lane & 15;
    const int q4   = lane >> 4;
    const int xm   = m16 & 7;

    const int id   = blockIdx.x;
    const int gid  = (id & 7) * (N_BLOCKS / 8) + (id >> 3);
    const int gsz  = GROUP_M * TN_TILES;
    const int grp  = gid / gsz;
    const int rem  = gid - grp * gsz;
    const int tn   = rem / GROUP_M;
    const int tm   = grp * GROUP_M + (rem - tn * GROUP_M);

    const int row0 = tm * 128;
    const int col0 = tn * 128;

    const int srow = tid >> 3;
    const int sj   = (tid & 7) ^ (srow & 7);

    f32x4 acc[4][4];
#pragma unroll
    for (int i = 0; i < 4; ++i)
#pragma unroll
        for (int j = 0; j < 4; ++j)
            acc[i][j] = (f32x4)0.0f;

    const float inv = 1.0f / act_s[0];
    const float* xSrc = X  + (size_t)(row0 + srow) * K_DIM + sj * 8;
    const int*   wSrc = Wt + (size_t)(col0 + srow) * K_DIM + sj * 8;

    _Float16* aDst = As + tid * 8;
    _Float16* bDst = Bs + tid * 8;

    for (int kk = 0; kk < K_DIM / 64; ++kk) {
#pragma unroll
        for (int i = 0; i < 4; ++i) {
            const float4* p = (const float4*)(xSrc + (size_t)i * 32 * K_DIM);
            float4 v0 = p[0];
            float4 v1 = p[1];
            half8 h;
            h[0] = (_Float16)rintf(v0.x * inv);
            h[1] = (_Float16)rintf(v0.y * inv);
            h[2] = (_Float16)rintf(v0.z * inv);
            h[3] = (_Float16)rintf(v0.w * inv);
            h[4] = (_Float16)rintf(v1.x * inv);
            h[5] = (_Float16)rintf(v1.y * inv);
            h[6] = (_Float16)rintf(v1.z * inv);
            h[7] = (_Float16)rintf(v1.w * inv);
            *(half8*)(aDst + i * 256 * 8) = h;
        }
#pragma unroll
        for (int i = 0; i < 4; ++i) {
            const int4* p = (const int4*)(wSrc + (size_t)i * 32 * K_DIM);
            int4 v0 = p[0];
            int4 v1 = p[1];
            half8 h;
            h[0] = (_Float16)v0.x;
            h[1] = (_Float16)v0.y;
            h[2] = (_Float16)v0.z;
            h[3] = (_Float16)v0.w;
            h[4] = (_Float16)v1.x;
            h[5] = (_Float16)v1.y;
            h[6] = (_Float16)v1.z;
            h[7] = (_Float16)v1.w;
            *(half8*)(bDst + i * 256 * 8) = h;
        }
        xSrc += 64;
        wSrc += 64;

        __syncthreads();

#pragma unroll
        for (int s = 0; s < 2; ++s) {
            half8 af[4], bf[4];
            const int chunk = (s * 4 + q4) ^ xm;
#pragma unroll
            for (int t = 0; t < 4; ++t) {
                af[t] = *(const half8*)(As + (wrow + t * 16 + m16) * 64 + chunk * 8);
                bf[t] = *(const half8*)(Bs + (wcol + t * 16 + m16) * 64 + chunk * 8);
            }
#pragma unroll
            for (int ti = 0; ti < 4; ++ti)
#pragma unroll
                for (int tj = 0; tj < 4; ++tj)
                    acc[ti][tj] = __builtin_amdgcn_mfma_f32_16x16x32_f16(
                        af[ti], bf[tj], acc[ti][tj], 0, 0, 0);
        }
        __syncthreads();
    }

#pragma unroll
    for (int tj = 0; tj < 4; ++tj) {
        const int n = col0 + wcol + tj * 16 + m16;
        const float sc = out_s[n];
#pragma unroll
        for (int ti = 0; ti < 4; ++ti) {
            const int rbase = row0 + wrow + ti * 16 + q4 * 4;
#pragma unroll
            for (int r = 0; r < 4; ++r) {
                __builtin_nontemporal_store(acc[ti][tj][r] * sc,
                    out + (size_t)(rbase + r) * N_DIM + n);
            }
        }
    }
}

extern "C" void kernel_launch(void* const* d_in, const int* in_sizes, int n_in,
                              void* d_out, int out_size, void* d_ws, size_t ws_size,
                              hipStream_t stream) {
    const float* x     = (const float*)d_in[0];
    const int*   w     = (const int*)d_in[1];
    const float* act_s = (const float*)d_in[2];
    const float* out_s = (const float*)d_in[3];
    float* out = (float*)d_out;

    const size_t bytesA = (size_t)M_DIM * K_DIM * sizeof(_Float16);   // 64 MiB
    const size_t bytesB = (size_t)N_DIM * K_DIM * sizeof(_Float16);   // 86 MiB

    if (ws_size >= bytesA + bytesB) {
        _Float16* Aq = (_Float16*)d_ws;
        _Float16* Bq = (_Float16*)((char*)d_ws + bytesA);
        quant_x_kernel<<<(int)(((size_t)M_DIM * K_DIM) / 2048), 256, 0, stream>>>(x, act_s, Aq);
        quant_w_kernel<<<(int)(((size_t)N_DIM * K_DIM) / 2048), 256, 0, stream>>>(w, Bq);
        w8a8_gemm<<<N_BLOCKS, 256, 0, stream>>>(Aq, Bq, out_s, out);
    } else {
        w8a8_gemm_fb<<<N_BLOCKS, 256, 0, stream>>>(x, w, act_s, out_s, out);
    }
}